// Round 1
// baseline (6691.448 us; speedup 1.0000x reference)
//
#include <hip/hip_runtime.h>
#include <math.h>

#define NEG_SLOPE 0.2f

// ---------- float<->ordered-uint encoding for atomicMax on floats ----------
__device__ __forceinline__ unsigned fenc(float f) {
    unsigned u = __float_as_uint(f);
    return (u & 0x80000000u) ? ~u : (u | 0x80000000u);
}
__device__ __forceinline__ float fdec(unsigned u) {
    u = (u & 0x80000000u) ? (u & 0x7fffffffu) : ~u;
    return __uint_as_float(u);
}

// ---------- fp32 tiled GEMM: C[M,N] = A[M,K] @ B[K,N], all row-major ------
// 64x64 tile per 256-thread block, K stepped by 16.
__global__ __launch_bounds__(256) void sgemm64(
    const float* __restrict__ A, const float* __restrict__ B,
    float* __restrict__ C, int M, int K, int N)
{
    __shared__ float As[16][64];  // [k][m]
    __shared__ float Bs[16][64];  // [k][n]
    const int tid = threadIdx.x;
    const int bm = blockIdx.x * 64;
    const int bn = blockIdx.y * 64;
    const int tx = tid & 15;      // n-subtile
    const int ty = tid >> 4;      // m-subtile
    const int ar = tid & 63, ac4 = (tid >> 6) * 4;   // A tile load coords
    const int br = tid >> 4, bc4 = (tid & 15) * 4;   // B tile load coords
    const int agr = bm + ar;
    float acc[4][4] = {};
    for (int kk = 0; kk < K; kk += 16) {
        float4 av = make_float4(0.f, 0.f, 0.f, 0.f);
        if (agr < M) av = *(const float4*)(A + (size_t)agr * K + kk + ac4);
        float4 bv = make_float4(0.f, 0.f, 0.f, 0.f);
        if (bn + bc4 < N) bv = *(const float4*)(B + (size_t)(kk + br) * N + bn + bc4);
        As[ac4 + 0][ar] = av.x; As[ac4 + 1][ar] = av.y;
        As[ac4 + 2][ar] = av.z; As[ac4 + 3][ar] = av.w;
        Bs[br][bc4 + 0] = bv.x; Bs[br][bc4 + 1] = bv.y;
        Bs[br][bc4 + 2] = bv.z; Bs[br][bc4 + 3] = bv.w;
        __syncthreads();
        #pragma unroll
        for (int k = 0; k < 16; ++k) {
            float a0 = As[k][ty * 4 + 0], a1 = As[k][ty * 4 + 1];
            float a2 = As[k][ty * 4 + 2], a3 = As[k][ty * 4 + 3];
            float b0 = Bs[k][tx * 4 + 0], b1 = Bs[k][tx * 4 + 1];
            float b2 = Bs[k][tx * 4 + 2], b3 = Bs[k][tx * 4 + 3];
            acc[0][0] += a0 * b0; acc[0][1] += a0 * b1; acc[0][2] += a0 * b2; acc[0][3] += a0 * b3;
            acc[1][0] += a1 * b0; acc[1][1] += a1 * b1; acc[1][2] += a1 * b2; acc[1][3] += a1 * b3;
            acc[2][0] += a2 * b0; acc[2][1] += a2 * b1; acc[2][2] += a2 * b2; acc[2][3] += a2 * b3;
            acc[3][0] += a3 * b0; acc[3][1] += a3 * b1; acc[3][2] += a3 * b2; acc[3][3] += a3 * b3;
        }
        __syncthreads();
    }
    #pragma unroll
    for (int i = 0; i < 4; ++i) {
        int row = bm + ty * 4 + i;
        int col = bn + tx * 4;
        if (row < M && col < N) {
            float4 v = make_float4(acc[i][0], acc[i][1], acc[i][2], acc[i][3]);
            *(float4*)(C + (size_t)row * N + col) = v;
        }
    }
}

// ---------- per-layer init: out = bias broadcast; m/denom reset -----------
__global__ __launch_bounds__(256) void init_out(float* __restrict__ out,
    const float* __restrict__ bias, int total, int hcMask)
{
    int i = blockIdx.x * 256 + threadIdx.x;
    if (i < total) out[i] = bias[i & hcMask];
}

__global__ __launch_bounds__(256) void init_md(unsigned* __restrict__ m,
    float* __restrict__ denom, int total)
{
    int i = blockIdx.x * 256 + threadIdx.x;
    if (i < total) { m[i] = 0u; denom[i] = 0.f; }
}

// ---------- edge logits + segment max, HC=256 (H=2, C=128) ----------------
// one wave per edge; lane handles 4 contiguous features (float4)
__global__ __launch_bounds__(256) void edge_logits_256(
    const float* __restrict__ xl, const float* __restrict__ xr,
    const float* __restrict__ att, const int* __restrict__ ei,
    float* __restrict__ logits, unsigned* __restrict__ mmax, int E0, int E)
{
    int e = blockIdx.x * 4 + (threadIdx.x >> 6);
    if (e >= E) return;
    int lane = threadIdx.x & 63;
    int s, d;
    if (e < E0) { s = ei[e]; d = ei[E0 + e]; } else { s = e - E0; d = s; }
    float4 a = *(const float4*)(xl + (size_t)s * 256 + lane * 4);
    float4 b = *(const float4*)(xr + (size_t)d * 256 + lane * 4);
    float4 w = *(const float4*)(att + lane * 4);
    float y, dot = 0.f;
    y = a.x + b.x; y = (y > 0.f) ? y : NEG_SLOPE * y; dot += y * w.x;
    y = a.y + b.y; y = (y > 0.f) ? y : NEG_SLOPE * y; dot += y * w.y;
    y = a.z + b.z; y = (y > 0.f) ? y : NEG_SLOPE * y; dot += y * w.z;
    y = a.w + b.w; y = (y > 0.f) ? y : NEG_SLOPE * y; dot += y * w.w;
    // butterfly sum within each 32-lane half (one head per half)
    #pragma unroll
    for (int mk = 1; mk < 32; mk <<= 1) dot += __shfl_xor(dot, mk, 64);
    if ((lane & 31) == 0) {
        int h = lane >> 5;
        logits[(size_t)e * 2 + h] = dot;
        atomicMax(mmax + (size_t)d * 2 + h, fenc(dot));
    }
}

// ---------- edge logits + segment max, HC=32 (H=1, C=32) ------------------
// one 32-lane half-wave per edge
__global__ __launch_bounds__(256) void edge_logits_32(
    const float* __restrict__ xl, const float* __restrict__ xr,
    const float* __restrict__ att, const int* __restrict__ ei,
    float* __restrict__ logits, unsigned* __restrict__ mmax, int E0, int E)
{
    int e = blockIdx.x * 8 + (threadIdx.x >> 5);
    if (e >= E) return;
    int c = threadIdx.x & 31;
    int s, d;
    if (e < E0) { s = ei[e]; d = ei[E0 + e]; } else { s = e - E0; d = s; }
    float y = xl[(size_t)s * 32 + c] + xr[(size_t)d * 32 + c];
    y = (y > 0.f) ? y : NEG_SLOPE * y;
    float dot = y * att[c];
    #pragma unroll
    for (int mk = 1; mk < 32; mk <<= 1) dot += __shfl_xor(dot, mk, 64);
    if (c == 0) {
        logits[e] = dot;
        atomicMax(mmax + d, fenc(dot));
    }
}

// ---------- exp(logit - max) + segment sum (in-place logits -> p) ---------
__global__ __launch_bounds__(256) void edge_exp(
    const int* __restrict__ ei, float* __restrict__ lp,
    const unsigned* __restrict__ mmax, float* __restrict__ denom,
    int E0, int E, int H)
{
    int i = blockIdx.x * 256 + threadIdx.x;
    if (i >= E * H) return;
    int e = (H == 2) ? (i >> 1) : i;
    int h = (H == 2) ? (i & 1) : 0;
    int d = (e < E0) ? ei[E0 + e] : e - E0;
    float p = expf(lp[i] - fdec(mmax[d * H + h]));
    lp[i] = p;
    atomicAdd(denom + (size_t)d * H + h, p);
}

// ---------- aggregation: out[dst] += alpha * xl[src], HC=256 --------------
__global__ __launch_bounds__(256) void edge_aggr_256(
    const float* __restrict__ xl, const float* __restrict__ p,
    const float* __restrict__ denom, const int* __restrict__ ei,
    float* __restrict__ out, int E0, int E)
{
    int e = blockIdx.x * 4 + (threadIdx.x >> 6);
    if (e >= E) return;
    int lane = threadIdx.x & 63;
    int s, d;
    if (e < E0) { s = ei[e]; d = ei[E0 + e]; } else { s = e - E0; d = s; }
    int h = lane >> 5;
    float alpha = p[(size_t)e * 2 + h] / denom[(size_t)d * 2 + h];
    float4 a = *(const float4*)(xl + (size_t)s * 256 + lane * 4);
    float* o = out + (size_t)d * 256 + lane * 4;
    atomicAdd(o + 0, alpha * a.x);
    atomicAdd(o + 1, alpha * a.y);
    atomicAdd(o + 2, alpha * a.z);
    atomicAdd(o + 3, alpha * a.w);
}

// ---------- aggregation, HC=32 --------------------------------------------
__global__ __launch_bounds__(256) void edge_aggr_32(
    const float* __restrict__ xl, const float* __restrict__ p,
    const float* __restrict__ denom, const int* __restrict__ ei,
    float* __restrict__ out, int E0, int E)
{
    int i = blockIdx.x * 256 + threadIdx.x;
    if (i >= E * 32) return;
    int e = i >> 5, c = i & 31;
    int s, d;
    if (e < E0) { s = ei[e]; d = ei[E0 + e]; } else { s = e - E0; d = s; }
    float alpha = p[e] / denom[d];
    atomicAdd(out + (size_t)d * 32 + c, alpha * xl[(size_t)s * 32 + c]);
}

extern "C" void kernel_launch(void* const* d_in, const int* in_sizes, int n_in,
                              void* d_out, int out_size, void* d_ws, size_t ws_size,
                              hipStream_t stream)
{
    const float* x  = (const float*)d_in[0];
    const int*   ei = (const int*)d_in[1];
    const float* Wl[4]   = {(const float*)d_in[2], (const float*)d_in[6], (const float*)d_in[10], (const float*)d_in[14]};
    const float* Wr[4]   = {(const float*)d_in[3], (const float*)d_in[7], (const float*)d_in[11], (const float*)d_in[15]};
    const float* attw[4] = {(const float*)d_in[4], (const float*)d_in[8], (const float*)d_in[12], (const float*)d_in[16]};
    const float* bias[4] = {(const float*)d_in[5], (const float*)d_in[9], (const float*)d_in[13], (const float*)d_in[17]};
    float* outp = (float*)d_out;

    const int N  = in_sizes[0] / 1024;   // 50000
    const int E0 = in_sizes[1] / 2;      // 400000
    const int E  = E0 + N;               // +self loops

    // workspace layout (floats)
    float* A  = (float*)d_ws;                       // N*256  (h / out rotating)
    float* Bx = A  + (size_t)N * 256;               // N*256  (xl)
    float* Cx = Bx + (size_t)N * 256;               // N*256  (xr)
    float* lg = Cx + (size_t)N * 256;               // E*2    (logits -> p, in place)
    float* dn = lg + (size_t)E * 2;                 // N*2    (softmax denom)
    unsigned* mm = (unsigned*)(dn + (size_t)N * 2); // N*2    (segment max, encoded)

    dim3 blk(256);
    const float* in = x;
    int fin = 1024;
    for (int l = 0; l < 4; ++l) {
        const int H  = (l == 3) ? 1 : 2;
        const int HC = (l == 3) ? 32 : 256;
        float* xl = Bx;
        float* xr = Cx;
        float* outl = (l == 3) ? outp : A;  // layer input (A) is dead after the 2 GEMMs

        dim3 g1((N + 63) / 64, (HC + 63) / 64);
        sgemm64<<<g1, blk, 0, stream>>>(in, Wl[l], xl, N, fin, HC);
        sgemm64<<<g1, blk, 0, stream>>>(in, Wr[l], xr, N, fin, HC);

        init_out<<<((size_t)N * HC + 255) / 256, blk, 0, stream>>>(outl, bias[l], N * HC, HC - 1);
        init_md<<<(N * H + 255) / 256, blk, 0, stream>>>(mm, dn, N * H);

        if (HC == 256) {
            edge_logits_256<<<(E + 3) / 4, blk, 0, stream>>>(xl, xr, attw[l], ei, lg, mm, E0, E);
            edge_exp<<<(E * 2 + 255) / 256, blk, 0, stream>>>(ei, lg, mm, dn, E0, E, 2);
            edge_aggr_256<<<(E + 3) / 4, blk, 0, stream>>>(xl, lg, dn, ei, outl, E0, E);
        } else {
            edge_logits_32<<<(E + 7) / 8, blk, 0, stream>>>(xl, xr, attw[l], ei, lg, mm, E0, E);
            edge_exp<<<(E + 255) / 256, blk, 0, stream>>>(ei, lg, mm, dn, E0, E, 1);
            edge_aggr_32<<<((size_t)E * 32 + 255) / 256, blk, 0, stream>>>(xl, lg, dn, ei, outl, E0, E);
        }
        in = A;
        fin = 256;
    }
}

// Round 2
// 1901.992 us; speedup vs baseline: 3.5181x; 3.5181x over previous
//
#include <hip/hip_runtime.h>
#include <math.h>

#define NEG_SLOPE 0.2f

// ---------- fp32 tiled GEMM: C[M,N] = A[M,K] @ B[K,N], all row-major ------
// 64x64 tile per 256-thread block, K stepped by 16.
__global__ __launch_bounds__(256) void sgemm64(
    const float* __restrict__ A, const float* __restrict__ B,
    float* __restrict__ C, int M, int K, int N)
{
    __shared__ float As[16][64];  // [k][m]
    __shared__ float Bs[16][64];  // [k][n]
    const int tid = threadIdx.x;
    const int bm = blockIdx.x * 64;
    const int bn = blockIdx.y * 64;
    const int tx = tid & 15;      // n-subtile
    const int ty = tid >> 4;      // m-subtile
    const int ar = tid & 63, ac4 = (tid >> 6) * 4;   // A tile load coords
    const int br = tid >> 4, bc4 = (tid & 15) * 4;   // B tile load coords
    const int agr = bm + ar;
    float acc[4][4] = {};
    for (int kk = 0; kk < K; kk += 16) {
        float4 av = make_float4(0.f, 0.f, 0.f, 0.f);
        if (agr < M) av = *(const float4*)(A + (size_t)agr * K + kk + ac4);
        float4 bv = make_float4(0.f, 0.f, 0.f, 0.f);
        if (bn + bc4 < N) bv = *(const float4*)(B + (size_t)(kk + br) * N + bn + bc4);
        As[ac4 + 0][ar] = av.x; As[ac4 + 1][ar] = av.y;
        As[ac4 + 2][ar] = av.z; As[ac4 + 3][ar] = av.w;
        Bs[br][bc4 + 0] = bv.x; Bs[br][bc4 + 1] = bv.y;
        Bs[br][bc4 + 2] = bv.z; Bs[br][bc4 + 3] = bv.w;
        __syncthreads();
        #pragma unroll
        for (int k = 0; k < 16; ++k) {
            float a0 = As[k][ty * 4 + 0], a1 = As[k][ty * 4 + 1];
            float a2 = As[k][ty * 4 + 2], a3 = As[k][ty * 4 + 3];
            float b0 = Bs[k][tx * 4 + 0], b1 = Bs[k][tx * 4 + 1];
            float b2 = Bs[k][tx * 4 + 2], b3 = Bs[k][tx * 4 + 3];
            acc[0][0] += a0 * b0; acc[0][1] += a0 * b1; acc[0][2] += a0 * b2; acc[0][3] += a0 * b3;
            acc[1][0] += a1 * b0; acc[1][1] += a1 * b1; acc[1][2] += a1 * b2; acc[1][3] += a1 * b3;
            acc[2][0] += a2 * b0; acc[2][1] += a2 * b1; acc[2][2] += a2 * b2; acc[2][3] += a2 * b3;
            acc[3][0] += a3 * b0; acc[3][1] += a3 * b1; acc[3][2] += a3 * b2; acc[3][3] += a3 * b3;
        }
        __syncthreads();
    }
    #pragma unroll
    for (int i = 0; i < 4; ++i) {
        int row = bm + ty * 4 + i;
        int col = bn + tx * 4;
        if (row < M && col < N) {
            float4 v = make_float4(acc[i][0], acc[i][1], acc[i][2], acc[i][3]);
            *(float4*)(C + (size_t)row * N + col) = v;
        }
    }
}

// ======================= CSR construction (per call) ======================
__global__ __launch_bounds__(256) void deg_zero(int* __restrict__ deg, int n)
{
    int i = blockIdx.x * 256 + threadIdx.x;
    if (i < n) deg[i] = 0;
}

__global__ __launch_bounds__(256) void deg_count(
    const int* __restrict__ ei, int* __restrict__ deg, int E0, int E)
{
    int e = blockIdx.x * 256 + threadIdx.x;
    if (e >= E) return;
    int d = (e < E0) ? ei[E0 + e] : e - E0;
    atomicAdd(deg + d, 1);
}

// phase 1: each block scans 1024 elems (256 thr x 4) -> per-block exclusive
// prefix written into rp, block total into bsums.
__global__ __launch_bounds__(256) void scan_blocks(
    const int* __restrict__ deg, int* __restrict__ rp,
    int* __restrict__ bsums, int n)
{
    __shared__ int sm[256];
    int base = blockIdx.x * 1024;
    int t = threadIdx.x;
    int i0 = base + t * 4;
    int v0 = (i0 + 0 < n) ? deg[i0 + 0] : 0;
    int v1 = (i0 + 1 < n) ? deg[i0 + 1] : 0;
    int v2 = (i0 + 2 < n) ? deg[i0 + 2] : 0;
    int v3 = (i0 + 3 < n) ? deg[i0 + 3] : 0;
    int tsum = v0 + v1 + v2 + v3;
    sm[t] = tsum;
    __syncthreads();
    for (int off = 1; off < 256; off <<= 1) {
        int val = (t >= off) ? sm[t - off] : 0;
        __syncthreads();
        sm[t] += val;
        __syncthreads();
    }
    int exb = sm[t] - tsum;   // exclusive base for this thread
    if (t == 255) bsums[blockIdx.x] = sm[255];
    if (i0 + 0 < n) rp[i0 + 0] = exb;
    if (i0 + 1 < n) rp[i0 + 1] = exb + v0;
    if (i0 + 2 < n) rp[i0 + 2] = exb + v0 + v1;
    if (i0 + 3 < n) rp[i0 + 3] = exb + v0 + v1 + v2;
}

// phase 2: exclusive scan of block sums (nb <= 64), single 64-thread block
__global__ void scan_bsums(int* __restrict__ bsums, int nb)
{
    __shared__ int sm[64];
    int t = threadIdx.x;
    int v = (t < nb) ? bsums[t] : 0;
    sm[t] = v;
    __syncthreads();
    for (int off = 1; off < 64; off <<= 1) {
        int val = (t >= off) ? sm[t - off] : 0;
        __syncthreads();
        sm[t] += val;
        __syncthreads();
    }
    if (t < nb) bsums[t] = sm[t] - v;  // exclusive
}

// phase 3: rp[i] += bsums_ex[i/1024]; duplicate into cursor
__global__ __launch_bounds__(256) void scan_finalize(
    int* __restrict__ rp, int* __restrict__ cur,
    const int* __restrict__ bsums, int n)
{
    int i = blockIdx.x * 256 + threadIdx.x;
    if (i < n) {
        int v = rp[i] + bsums[i >> 10];
        rp[i] = v;
        cur[i] = v;
    }
}

__global__ __launch_bounds__(256) void csr_fill(
    const int* __restrict__ ei, int* __restrict__ cur,
    int* __restrict__ csrc, int E0, int E)
{
    int e = blockIdx.x * 256 + threadIdx.x;
    if (e >= E) return;
    int s, d;
    if (e < E0) { s = ei[e]; d = ei[E0 + e]; } else { s = e - E0; d = s; }
    int pos = atomicAdd(cur + d, 1);
    csrc[pos] = s;
}

// ============ fused GATv2 attention + aggregation, HC=256 (H=2,C=128) =====
// One wave per dst node; lanes 0-31 = head 0, lanes 32-63 = head 1;
// each lane owns 4 contiguous features. Online softmax, zero atomics.
__global__ __launch_bounds__(256) void aggr_csr_256(
    const float* __restrict__ xl, const float* __restrict__ xr,
    const float* __restrict__ att, const float* __restrict__ bias,
    const int* __restrict__ csrc, const int* __restrict__ rp,
    const int* __restrict__ deg, float* __restrict__ out, int N)
{
    int node = blockIdx.x * 4 + (threadIdx.x >> 6);
    if (node >= N) return;
    int lane = threadIdx.x & 63;
    float4 b = *(const float4*)(xr + (size_t)node * 256 + lane * 4);
    float4 w = *(const float4*)(att + lane * 4);
    int start = rp[node];
    int g = deg[node];
    float m = -INFINITY, l = 0.f;
    float4 acc = make_float4(0.f, 0.f, 0.f, 0.f);
    for (int j = 0; j < g; ++j) {
        int s = csrc[start + j];
        float4 a = *(const float4*)(xl + (size_t)s * 256 + lane * 4);
        float y, dot = 0.f;
        y = a.x + b.x; y = (y > 0.f) ? y : NEG_SLOPE * y; dot += y * w.x;
        y = a.y + b.y; y = (y > 0.f) ? y : NEG_SLOPE * y; dot += y * w.y;
        y = a.z + b.z; y = (y > 0.f) ? y : NEG_SLOPE * y; dot += y * w.z;
        y = a.w + b.w; y = (y > 0.f) ? y : NEG_SLOPE * y; dot += y * w.w;
        #pragma unroll
        for (int mk = 1; mk < 32; mk <<= 1) dot += __shfl_xor(dot, mk, 64);
        // every lane in each 32-half now has its head's logit
        float mn = fmaxf(m, dot);
        float scale = __expf(m - mn);   // first iter: exp(-inf) = 0
        float p = __expf(dot - mn);
        l = l * scale + p;
        acc.x = acc.x * scale + p * a.x;
        acc.y = acc.y * scale + p * a.y;
        acc.z = acc.z * scale + p * a.z;
        acc.w = acc.w * scale + p * a.w;
        m = mn;
    }
    float inv = 1.f / l;
    float4 bi = *(const float4*)(bias + lane * 4);
    float4 o;
    o.x = acc.x * inv + bi.x;
    o.y = acc.y * inv + bi.y;
    o.z = acc.z * inv + bi.z;
    o.w = acc.w * inv + bi.w;
    *(float4*)(out + (size_t)node * 256 + lane * 4) = o;
}

// ============ fused attention + aggregation, HC=32 (H=1,C=32) =============
// 8 lanes per dst node (8 nodes per wave); each lane owns 4 features.
__global__ __launch_bounds__(256) void aggr_csr_32(
    const float* __restrict__ xl, const float* __restrict__ xr,
    const float* __restrict__ att, const float* __restrict__ bias,
    const int* __restrict__ csrc, const int* __restrict__ rp,
    const int* __restrict__ deg, float* __restrict__ out, int N)
{
    int node = blockIdx.x * 32 + (threadIdx.x >> 3);
    if (node >= N) return;
    int lane8 = threadIdx.x & 7;
    float4 b = *(const float4*)(xr + (size_t)node * 32 + lane8 * 4);
    float4 w = *(const float4*)(att + lane8 * 4);
    int start = rp[node];
    int g = deg[node];
    float m = -INFINITY, l = 0.f;
    float4 acc = make_float4(0.f, 0.f, 0.f, 0.f);
    for (int j = 0; j < g; ++j) {
        int s = csrc[start + j];
        float4 a = *(const float4*)(xl + (size_t)s * 32 + lane8 * 4);
        float y, dot = 0.f;
        y = a.x + b.x; y = (y > 0.f) ? y : NEG_SLOPE * y; dot += y * w.x;
        y = a.y + b.y; y = (y > 0.f) ? y : NEG_SLOPE * y; dot += y * w.y;
        y = a.z + b.z; y = (y > 0.f) ? y : NEG_SLOPE * y; dot += y * w.z;
        y = a.w + b.w; y = (y > 0.f) ? y : NEG_SLOPE * y; dot += y * w.w;
        #pragma unroll
        for (int mk = 1; mk < 8; mk <<= 1) dot += __shfl_xor(dot, mk, 64);
        float mn = fmaxf(m, dot);
        float scale = __expf(m - mn);
        float p = __expf(dot - mn);
        l = l * scale + p;
        acc.x = acc.x * scale + p * a.x;
        acc.y = acc.y * scale + p * a.y;
        acc.z = acc.z * scale + p * a.z;
        acc.w = acc.w * scale + p * a.w;
        m = mn;
    }
    float inv = 1.f / l;
    float4 bi = *(const float4*)(bias + lane8 * 4);
    float4 o;
    o.x = acc.x * inv + bi.x;
    o.y = acc.y * inv + bi.y;
    o.z = acc.z * inv + bi.z;
    o.w = acc.w * inv + bi.w;
    *(float4*)(out + (size_t)node * 32 + lane8 * 4) = o;
}

extern "C" void kernel_launch(void* const* d_in, const int* in_sizes, int n_in,
                              void* d_out, int out_size, void* d_ws, size_t ws_size,
                              hipStream_t stream)
{
    const float* x  = (const float*)d_in[0];
    const int*   ei = (const int*)d_in[1];
    const float* Wl[4]   = {(const float*)d_in[2], (const float*)d_in[6], (const float*)d_in[10], (const float*)d_in[14]};
    const float* Wr[4]   = {(const float*)d_in[3], (const float*)d_in[7], (const float*)d_in[11], (const float*)d_in[15]};
    const float* attw[4] = {(const float*)d_in[4], (const float*)d_in[8], (const float*)d_in[12], (const float*)d_in[16]};
    const float* bias[4] = {(const float*)d_in[5], (const float*)d_in[9], (const float*)d_in[13], (const float*)d_in[17]};
    float* outp = (float*)d_out;

    const int N  = in_sizes[0] / 1024;   // 50000
    const int E0 = in_sizes[1] / 2;      // 400000
    const int E  = E0 + N;               // +self loops
    const int NB = (N + 1023) / 1024;    // scan blocks (<= 64)

    // workspace layout
    float* A   = (float*)d_ws;                      // N*256 (h rotating)
    float* Bx  = A  + (size_t)N * 256;              // N*256 (xl)
    float* Cx  = Bx + (size_t)N * 256;              // N*256 (xr)
    int*   deg = (int*)(Cx + (size_t)N * 256);      // N
    int*   rp  = deg + N;                           // N
    int*   cur = rp + N;                            // N
    int*   bsums = cur + N;                         // <=64
    int*   csrc  = bsums + 64;                      // E

    dim3 blk(256);

    // ---- build CSR (graph is identical for all 4 layers) ----
    deg_zero<<<(N + 255) / 256, blk, 0, stream>>>(deg, N);
    deg_count<<<(E + 255) / 256, blk, 0, stream>>>(ei, deg, E0, E);
    scan_blocks<<<NB, blk, 0, stream>>>(deg, rp, bsums, N);
    scan_bsums<<<1, 64, 0, stream>>>(bsums, NB);
    scan_finalize<<<(N + 255) / 256, blk, 0, stream>>>(rp, cur, bsums, N);
    csr_fill<<<(E + 255) / 256, blk, 0, stream>>>(ei, cur, csrc, E0, E);

    // ---- layers ----
    const float* in = x;
    int fin = 1024;
    for (int l = 0; l < 4; ++l) {
        const int HC = (l == 3) ? 32 : 256;
        float* xl = Bx;
        float* xr = Cx;
        float* outl = (l == 3) ? outp : A;  // layer input (A) dead after GEMMs

        dim3 g1((N + 63) / 64, (HC + 63) / 64);
        sgemm64<<<g1, blk, 0, stream>>>(in, Wl[l], xl, N, fin, HC);
        sgemm64<<<g1, blk, 0, stream>>>(in, Wr[l], xr, N, fin, HC);

        if (HC == 256) {
            aggr_csr_256<<<(N + 3) / 4, blk, 0, stream>>>(
                xl, xr, attw[l], bias[l], csrc, rp, deg, outl, N);
        } else {
            aggr_csr_32<<<(N + 31) / 32, blk, 0, stream>>>(
                xl, xr, attw[l], bias[l], csrc, rp, deg, outl, N);
        }
        in = A;
        fin = 256;
    }
}

// Round 3
// 778.313 us; speedup vs baseline: 8.5974x; 2.4437x over previous
//
#include <hip/hip_runtime.h>
#include <math.h>

#define NEG_SLOPE 0.2f

typedef __attribute__((ext_vector_type(8))) short bf16x8;
typedef __attribute__((ext_vector_type(4))) float f32x4;

// ---------------- bf16 helpers (RNE) ----------------
__device__ __forceinline__ float b2f(unsigned short u) {
    return __uint_as_float(((unsigned)u) << 16);
}
__device__ __forceinline__ unsigned short f2b(float f) {
    unsigned u = __float_as_uint(f);
    unsigned r = (u + 0x7fffu + ((u >> 16) & 1u)) >> 16;
    return (unsigned short)r;
}

// ---------------- async global->LDS 16B ----------------
__device__ __forceinline__ void async_copy16(const void* g, void* l) {
    __builtin_amdgcn_global_load_lds(
        (const __attribute__((address_space(1))) void*)g,
        (__attribute__((address_space(3))) void*)l, 16, 0, 0);
}

// ============== bf16 MFMA GEMM: C[M][Nc] = A[M][K] @ Bt[Nc][K]^T ==========
// 128x128 tile / 256 threads (4 waves, 2x2), BK=32, 16x16x32 MFMA.
// LDS quads XOR-swizzled by ((row>>1)&3) -> 2-way bank aliasing (free).
__global__ __launch_bounds__(256) void gemm_bf16(
    const unsigned short* __restrict__ A,   // [M][K] bf16
    const unsigned short* __restrict__ Bt,  // [Nc][K] bf16 (pre-transposed)
    unsigned short* __restrict__ C,         // [M][Nc] bf16
    int M, int K, int Nc)
{
    __shared__ unsigned short As[128 * 32];
    __shared__ unsigned short Bs[128 * 32];
    const int tid = threadIdx.x;
    const int w = tid >> 6, lane = tid & 63;
    const int tm = blockIdx.x * 128;
    const int tn = blockIdx.y * 128;

    // staging slot mapping: off16 = r*256 + w*64 + lane (16B slots)
    const int off0 = w * 64 + lane;
    const int row0 = off0 >> 2, q0 = off0 & 3;
    const int qg0 = q0 ^ ((row0 >> 1) & 3);
    const int off1 = 256 + w * 64 + lane;
    const int row1 = off1 >> 2, q1 = off1 & 3;
    const int qg1 = q1 ^ ((row1 >> 1) & 3);

    const int ar0 = min(tm + row0, M - 1), ar1 = min(tm + row1, M - 1);
    const int bn0 = min(tn + row0, Nc - 1), bn1 = min(tn + row1, Nc - 1);
    const unsigned short* pa0 = A + (size_t)ar0 * K + qg0 * 8;
    const unsigned short* pa1 = A + (size_t)ar1 * K + qg1 * 8;
    const unsigned short* pb0 = Bt + (size_t)bn0 * K + qg0 * 8;
    const unsigned short* pb1 = Bt + (size_t)bn1 * K + qg1 * 8;
    // wave-uniform LDS bases (HW adds lane*16)
    unsigned short* lA0 = As + (size_t)(w * 64) * 8;
    unsigned short* lA1 = As + (size_t)(256 + w * 64) * 8;
    unsigned short* lB0 = Bs + (size_t)(w * 64) * 8;
    unsigned short* lB1 = Bs + (size_t)(256 + w * 64) * 8;

    // fragment LDS read pointers
    const int m0 = (w & 1) * 64, n0 = (w >> 1) * 64;
    const int fr = lane & 15, Q = lane >> 4;
    const unsigned short* aptr[4];
    const unsigned short* bptr[4];
    #pragma unroll
    for (int i = 0; i < 4; ++i) {
        int ra = m0 + i * 16 + fr;
        aptr[i] = As + (ra * 64 + ((Q ^ ((ra >> 1) & 3)) * 16)) / 2;
        int rb = n0 + i * 16 + fr;
        bptr[i] = Bs + (rb * 64 + ((Q ^ ((rb >> 1) & 3)) * 16)) / 2;
    }

    f32x4 acc[4][4] = {};
    for (int kk = 0; kk < K; kk += 32) {
        async_copy16(pa0 + kk, lA0);
        async_copy16(pa1 + kk, lA1);
        async_copy16(pb0 + kk, lB0);
        async_copy16(pb1 + kk, lB1);
        __syncthreads();
        bf16x8 af[4], bfr[4];
        #pragma unroll
        for (int i = 0; i < 4; ++i) {
            af[i]  = *(const bf16x8*)aptr[i];
            bfr[i] = *(const bf16x8*)bptr[i];
        }
        #pragma unroll
        for (int mi = 0; mi < 4; ++mi)
            #pragma unroll
            for (int ni = 0; ni < 4; ++ni)
                acc[mi][ni] = __builtin_amdgcn_mfma_f32_16x16x32_bf16(
                    af[mi], bfr[ni], acc[mi][ni], 0, 0, 0);
        __syncthreads();
    }

    // epilogue: C/D layout col=lane&15, row=(lane>>4)*4+reg
    #pragma unroll
    for (int mi = 0; mi < 4; ++mi) {
        #pragma unroll
        for (int ni = 0; ni < 4; ++ni) {
            int col = tn + n0 + ni * 16 + fr;
            #pragma unroll
            for (int r = 0; r < 4; ++r) {
                int row = tm + m0 + mi * 16 + Q * 4 + r;
                if (row < M && col < Nc)
                    C[(size_t)row * Nc + col] = f2b(acc[mi][ni][r]);
            }
        }
    }
}

// ---------------- conversions ----------------
__global__ __launch_bounds__(256) void cvt_f2b(
    const float* __restrict__ in, unsigned short* __restrict__ outp, int total4)
{
    int i = blockIdx.x * 256 + threadIdx.x;
    if (i >= total4) return;
    float4 v = ((const float4*)in)[i];
    ushort4 o = make_ushort4(f2b(v.x), f2b(v.y), f2b(v.z), f2b(v.w));
    ((ushort4*)outp)[i] = o;
}

// WT[n][k] = bf16( n<HC ? Wl[k][n] : Wr[k][n-HC] )
__global__ __launch_bounds__(256) void cvt_wt(
    const float* __restrict__ Wl, const float* __restrict__ Wr,
    unsigned short* __restrict__ WT, int fin, int HC)
{
    int id = blockIdx.x * 256 + threadIdx.x;
    int total = fin * 2 * HC;
    if (id >= total) return;
    int n = id / fin, k = id - n * fin;
    float v = (n < HC) ? Wl[(size_t)k * HC + n] : Wr[(size_t)k * HC + (n - HC)];
    WT[id] = f2b(v);
}

// ======================= CSR construction (per call) ======================
__global__ __launch_bounds__(256) void deg_zero(int* __restrict__ deg, int n)
{
    int i = blockIdx.x * 256 + threadIdx.x;
    if (i < n) deg[i] = 0;
}

__global__ __launch_bounds__(256) void deg_count(
    const int* __restrict__ ei, int* __restrict__ deg, int E0, int E)
{
    int e = blockIdx.x * 256 + threadIdx.x;
    if (e >= E) return;
    int d = (e < E0) ? ei[E0 + e] : e - E0;
    atomicAdd(deg + d, 1);
}

__global__ __launch_bounds__(256) void scan_blocks(
    const int* __restrict__ deg, int* __restrict__ rp,
    int* __restrict__ bsums, int n)
{
    __shared__ int sm[256];
    int base = blockIdx.x * 1024;
    int t = threadIdx.x;
    int i0 = base + t * 4;
    int v0 = (i0 + 0 < n) ? deg[i0 + 0] : 0;
    int v1 = (i0 + 1 < n) ? deg[i0 + 1] : 0;
    int v2 = (i0 + 2 < n) ? deg[i0 + 2] : 0;
    int v3 = (i0 + 3 < n) ? deg[i0 + 3] : 0;
    int tsum = v0 + v1 + v2 + v3;
    sm[t] = tsum;
    __syncthreads();
    for (int off = 1; off < 256; off <<= 1) {
        int val = (t >= off) ? sm[t - off] : 0;
        __syncthreads();
        sm[t] += val;
        __syncthreads();
    }
    int exb = sm[t] - tsum;
    if (t == 255) bsums[blockIdx.x] = sm[255];
    if (i0 + 0 < n) rp[i0 + 0] = exb;
    if (i0 + 1 < n) rp[i0 + 1] = exb + v0;
    if (i0 + 2 < n) rp[i0 + 2] = exb + v0 + v1;
    if (i0 + 3 < n) rp[i0 + 3] = exb + v0 + v1 + v2;
}

__global__ void scan_bsums(int* __restrict__ bsums, int nb)
{
    __shared__ int sm[64];
    int t = threadIdx.x;
    int v = (t < nb) ? bsums[t] : 0;
    sm[t] = v;
    __syncthreads();
    for (int off = 1; off < 64; off <<= 1) {
        int val = (t >= off) ? sm[t - off] : 0;
        __syncthreads();
        sm[t] += val;
        __syncthreads();
    }
    if (t < nb) bsums[t] = sm[t] - v;
}

__global__ __launch_bounds__(256) void scan_finalize(
    int* __restrict__ rp, int* __restrict__ cur,
    const int* __restrict__ bsums, int n)
{
    int i = blockIdx.x * 256 + threadIdx.x;
    if (i < n) {
        int v = rp[i] + bsums[i >> 10];
        rp[i] = v;
        cur[i] = v;
    }
}

__global__ __launch_bounds__(256) void csr_fill(
    const int* __restrict__ ei, int* __restrict__ cur,
    int* __restrict__ csrc, int E0, int E)
{
    int e = blockIdx.x * 256 + threadIdx.x;
    if (e >= E) return;
    int s, d;
    if (e < E0) { s = ei[e]; d = ei[E0 + e]; } else { s = e - E0; d = s; }
    int pos = atomicAdd(cur + d, 1);
    csrc[pos] = s;
}

// ====== fused GATv2 attention + aggregation, HC=256 (H=2,C=128), bf16 =====
// One wave per dst node; lanes 0-31 head 0, 32-63 head 1; 4 features/lane.
// Reads bf16 xlr [N][512] (xl=+0, xr=+256); writes bf16 h [N][256].
__global__ __launch_bounds__(256) void aggr_csr_256(
    const unsigned short* __restrict__ xlr,
    const float* __restrict__ att, const float* __restrict__ bias,
    const int* __restrict__ csrc, const int* __restrict__ rp,
    const int* __restrict__ deg, unsigned short* __restrict__ outb, int N)
{
    int node = blockIdx.x * 4 + (threadIdx.x >> 6);
    if (node >= N) return;
    int lane = threadIdx.x & 63;
    ushort4 bu = *(const ushort4*)(xlr + (size_t)node * 512 + 256 + lane * 4);
    float bx = b2f(bu.x), by = b2f(bu.y), bz = b2f(bu.z), bw = b2f(bu.w);
    float4 wv = *(const float4*)(att + lane * 4);
    int start = rp[node];
    int g = deg[node];
    float m = -INFINITY, l = 0.f;
    float4 acc = make_float4(0.f, 0.f, 0.f, 0.f);
    for (int j = 0; j < g; ++j) {
        int s = csrc[start + j];
        ushort4 au = *(const ushort4*)(xlr + (size_t)s * 512 + lane * 4);
        float ax = b2f(au.x), ay = b2f(au.y), az = b2f(au.z), aw = b2f(au.w);
        float y, dot = 0.f;
        y = ax + bx; y = (y > 0.f) ? y : NEG_SLOPE * y; dot += y * wv.x;
        y = ay + by; y = (y > 0.f) ? y : NEG_SLOPE * y; dot += y * wv.y;
        y = az + bz; y = (y > 0.f) ? y : NEG_SLOPE * y; dot += y * wv.z;
        y = aw + bw; y = (y > 0.f) ? y : NEG_SLOPE * y; dot += y * wv.w;
        #pragma unroll
        for (int mk = 1; mk < 32; mk <<= 1) dot += __shfl_xor(dot, mk, 64);
        float mn = fmaxf(m, dot);
        float scale = __expf(m - mn);   // first iter: exp(-inf) = 0
        float p = __expf(dot - mn);
        l = l * scale + p;
        acc.x = acc.x * scale + p * ax;
        acc.y = acc.y * scale + p * ay;
        acc.z = acc.z * scale + p * az;
        acc.w = acc.w * scale + p * aw;
        m = mn;
    }
    float inv = 1.f / l;
    float4 bi = *(const float4*)(bias + lane * 4);
    ushort4 o = make_ushort4(f2b(acc.x * inv + bi.x), f2b(acc.y * inv + bi.y),
                             f2b(acc.z * inv + bi.z), f2b(acc.w * inv + bi.w));
    *(ushort4*)(outb + (size_t)node * 256 + lane * 4) = o;
}

// ===== fused attention + aggregation, HC=32 (H=1,C=32), final layer =======
// 8 lanes per dst node; reads bf16 xlr [N][64] (xl=+0, xr=+32), writes fp32.
__global__ __launch_bounds__(256) void aggr_csr_32(
    const unsigned short* __restrict__ xlr,
    const float* __restrict__ att, const float* __restrict__ bias,
    const int* __restrict__ csrc, const int* __restrict__ rp,
    const int* __restrict__ deg, float* __restrict__ out, int N)
{
    int node = blockIdx.x * 32 + (threadIdx.x >> 3);
    if (node >= N) return;
    int lane8 = threadIdx.x & 7;
    ushort4 bu = *(const ushort4*)(xlr + (size_t)node * 64 + 32 + lane8 * 4);
    float bx = b2f(bu.x), by = b2f(bu.y), bz = b2f(bu.z), bw = b2f(bu.w);
    float4 wv = *(const float4*)(att + lane8 * 4);
    int start = rp[node];
    int g = deg[node];
    float m = -INFINITY, l = 0.f;
    float4 acc = make_float4(0.f, 0.f, 0.f, 0.f);
    for (int j = 0; j < g; ++j) {
        int s = csrc[start + j];
        ushort4 au = *(const ushort4*)(xlr + (size_t)s * 64 + lane8 * 4);
        float ax = b2f(au.x), ay = b2f(au.y), az = b2f(au.z), aw = b2f(au.w);
        float y, dot = 0.f;
        y = ax + bx; y = (y > 0.f) ? y : NEG_SLOPE * y; dot += y * wv.x;
        y = ay + by; y = (y > 0.f) ? y : NEG_SLOPE * y; dot += y * wv.y;
        y = az + bz; y = (y > 0.f) ? y : NEG_SLOPE * y; dot += y * wv.z;
        y = aw + bw; y = (y > 0.f) ? y : NEG_SLOPE * y; dot += y * wv.w;
        #pragma unroll
        for (int mk = 1; mk < 8; mk <<= 1) dot += __shfl_xor(dot, mk, 64);
        float mn = fmaxf(m, dot);
        float scale = __expf(m - mn);
        float p = __expf(dot - mn);
        l = l * scale + p;
        acc.x = acc.x * scale + p * ax;
        acc.y = acc.y * scale + p * ay;
        acc.z = acc.z * scale + p * az;
        acc.w = acc.w * scale + p * aw;
        m = mn;
    }
    float inv = 1.f / l;
    float4 bi = *(const float4*)(bias + lane8 * 4);
    float4 o;
    o.x = acc.x * inv + bi.x;
    o.y = acc.y * inv + bi.y;
    o.z = acc.z * inv + bi.z;
    o.w = acc.w * inv + bi.w;
    *(float4*)(out + (size_t)node * 32 + lane8 * 4) = o;
}

extern "C" void kernel_launch(void* const* d_in, const int* in_sizes, int n_in,
                              void* d_out, int out_size, void* d_ws, size_t ws_size,
                              hipStream_t stream)
{
    const float* x  = (const float*)d_in[0];
    const int*   ei = (const int*)d_in[1];
    const float* Wl[4]   = {(const float*)d_in[2], (const float*)d_in[6], (const float*)d_in[10], (const float*)d_in[14]};
    const float* Wr[4]   = {(const float*)d_in[3], (const float*)d_in[7], (const float*)d_in[11], (const float*)d_in[15]};
    const float* attw[4] = {(const float*)d_in[4], (const float*)d_in[8], (const float*)d_in[12], (const float*)d_in[16]};
    const float* bias[4] = {(const float*)d_in[5], (const float*)d_in[9], (const float*)d_in[13], (const float*)d_in[17]};
    float* outp = (float*)d_out;

    const int N  = in_sizes[0] / 1024;   // 50000
    const int E0 = in_sizes[1] / 2;      // 400000
    const int E  = E0 + N;               // +self loops
    const int NB = (N + 1023) / 1024;

    // workspace layout
    int* deg   = (int*)d_ws;                         // N
    int* rp    = deg + N;                            // N
    int* cur   = rp + N;                             // N
    int* bsums = cur + N;                            // 64
    int* csrc  = bsums + 64;                         // E
    unsigned short* WT  = (unsigned short*)(csrc + E);      // 512*1024 max
    unsigned short* xb  = WT + 512 * 1024;                  // N*1024 bf16
    unsigned short* hb  = xb;                               // alias: xb dead after L0 GEMM
    unsigned short* xlr = xb + (size_t)N * 1024;            // N*512 bf16

    dim3 blk(256);

    // ---- build CSR (shared by all layers) ----
    deg_zero<<<(N + 255) / 256, blk, 0, stream>>>(deg, N);
    deg_count<<<(E + 255) / 256, blk, 0, stream>>>(ei, deg, E0, E);
    scan_blocks<<<NB, blk, 0, stream>>>(deg, rp, bsums, N);
    scan_bsums<<<1, 64, 0, stream>>>(bsums, NB);
    scan_finalize<<<(N + 255) / 256, blk, 0, stream>>>(rp, cur, bsums, N);
    csr_fill<<<(E + 255) / 256, blk, 0, stream>>>(ei, cur, csrc, E0, E);

    // ---- x -> bf16 ----
    cvt_f2b<<<((size_t)N * 1024 / 4 + 255) / 256, blk, 0, stream>>>(x, xb, N * 1024 / 4);

    const int gm = (N + 127) / 128;
    for (int l = 0; l < 4; ++l) {
        const int HC  = (l == 3) ? 32 : 256;
        const int fin = (l == 0) ? 1024 : 256;
        const int Nc  = 2 * HC;
        const unsigned short* Ain = (l == 0) ? xb : hb;

        cvt_wt<<<(fin * Nc + 255) / 256, blk, 0, stream>>>(Wl[l], Wr[l], WT, fin, HC);
        gemm_bf16<<<dim3(gm, (Nc + 127) / 128), blk, 0, stream>>>(Ain, WT, xlr, N, fin, Nc);

        if (l < 3) {
            aggr_csr_256<<<(N + 3) / 4, blk, 0, stream>>>(
                xlr, attw[l], bias[l], csrc, rp, deg, hb, N);
        } else {
            aggr_csr_32<<<(N + 31) / 32, blk, 0, stream>>>(
                xlr, attw[l], bias[l], csrc, rp, deg, outp, N);
        }
    }
}